// Round 2
// baseline (815.534 us; speedup 1.0000x reference)
//
#include <hip/hip_runtime.h>
#include <hip/hip_bf16.h>
#include <math.h>

#define O_ 1024
#define D_ 1024
#define E_ 16
#define K_ 4
#define H_ 2048
#define A_ 64
#define LOSS_COEF 0.01f

#define BM 64
#define BN 64
#define BK 16

// FLT_MIN: smallest normal fp32. The np reference runs with FTZ/DAZ (evidence:
// its min log_prob is log(FLT_MIN) ~= -87.3, never in the subnormal band), while
// gfx950 HIP keeps IEEE f32 denormals. We emulate the reference's FTZ in
// software at the two points where it decides the p==0 branch.
#define FLT_MIN_NORMAL 1.17549435e-38f

// ---------------------------------------------------------------------------
// gating: logits[o,e] = sum_d obs[o,d]*w_gate[o,d,e]; top-4, softmax, loss inputs
// ---------------------------------------------------------------------------
__global__ __launch_bounds__(256) void gating_kernel(
    const float* __restrict__ obs, const float* __restrict__ w_gate,
    int* __restrict__ topk_idx, float* __restrict__ topk_gate,
    float* __restrict__ imp, float* __restrict__ loadv)
{
    const int o = blockIdx.x;
    const int t = threadIdx.x;
    __shared__ float xs[D_];
    __shared__ float part[256];
    __shared__ float logits[E_];

    const float4* xrow = (const float4*)(obs + (size_t)o * D_);
    for (int i = t; i < D_ / 4; i += 256) ((float4*)xs)[i] = xrow[i];
    __syncthreads();

    const int e = t & 15, dg = t >> 4;
    const float* wg = w_gate + (size_t)o * (D_ * E_);
    float acc = 0.f;
    #pragma unroll 4
    for (int i = 0; i < D_ / 16; ++i) {
        int d = dg + (i << 4);
        acc += xs[d] * wg[(size_t)d * E_ + e];   // addr = t + 256*i: coalesced
    }
    part[t] = acc;
    __syncthreads();
    if (t < E_) {
        float s = 0.f;
        #pragma unroll
        for (int g = 0; g < 16; ++g) s += part[g * 16 + t];
        logits[t] = s;
    }
    __syncthreads();
    if (t == 0) {
        float lv[E_];
        #pragma unroll
        for (int i = 0; i < E_; ++i) lv[i] = logits[i];
        int idx[K_]; float val[K_];
        bool used[E_] = {};
        for (int k = 0; k < K_; ++k) {            // jax top_k: desc, ties -> lower idx
            int bi = 0; float bv = -INFINITY;
            for (int i = 0; i < E_; ++i)
                if (!used[i] && lv[i] > bv) { bv = lv[i]; bi = i; }
            used[bi] = true; idx[k] = bi; val[k] = bv;
        }
        float m = val[0];
        float ex[K_]; float s = 0.f;
        for (int k = 0; k < K_; ++k) { ex[k] = expf(val[k] - m); s += ex[k]; }
        float inv = 1.f / s;
        float sumg = 0.f; int ld = 0;
        for (int k = 0; k < K_; ++k) {
            float g = ex[k] * inv;
            topk_idx[o * K_ + k] = idx[k];
            topk_gate[o * K_ + k] = g;
            sumg += g;
            if (g > 0.f) ld++;
        }
        imp[o] = sumg;
        loadv[o] = (float)ld;
    }
}

// ---------------------------------------------------------------------------
__global__ void zero_cnt_kernel(int* __restrict__ cnt)
{
    if (threadIdx.x < E_) cnt[threadIdx.x] = 0;
}

__global__ __launch_bounds__(256) void build_dispatch_kernel(
    const int* __restrict__ topk_idx, const float* __restrict__ topk_gate,
    int* __restrict__ cnt, int* __restrict__ rows, float* __restrict__ gatev)
{
    int i = blockIdx.x * 256 + threadIdx.x;      // 0..O*K-1
    int e = topk_idx[i];
    int pos = atomicAdd(&cnt[e], 1);
    rows[e * O_ + pos] = i >> 2;
    gatev[e * O_ + pos] = topk_gate[i];
}

// y[o,a] = sum_k gate[o,k]*b2[e_k,a]  (init so GEMM can atomicAdd on top)
__global__ __launch_bounds__(64) void y_init_kernel(
    const int* __restrict__ topk_idx, const float* __restrict__ topk_gate,
    const float* __restrict__ b2, float* __restrict__ y)
{
    int o = blockIdx.x, a = threadIdx.x;
    float acc = 0.f;
    #pragma unroll
    for (int k = 0; k < K_; ++k) {
        int e = topk_idx[o * K_ + k];
        acc += topk_gate[o * K_ + k] * b2[e * A_ + a];
    }
    y[(size_t)o * A_ + a] = acc;
}

// ---------------------------------------------------------------------------
// loss = 0.01*(cv2(importance)+cv2(load)), two-pass var (ddof=1)
// ---------------------------------------------------------------------------
__global__ __launch_bounds__(1024) void loss_kernel(
    const float* __restrict__ imp, const float* __restrict__ loadv,
    float* __restrict__ out_loss)
{
    __shared__ float s1[1024], s2[1024];
    __shared__ float mean1, mean2;
    int t = threadIdx.x;
    float a = imp[t], b = loadv[t];
    s1[t] = a; s2[t] = b; __syncthreads();
    for (int s = 512; s > 0; s >>= 1) {
        if (t < s) { s1[t] += s1[t + s]; s2[t] += s2[t + s]; }
        __syncthreads();
    }
    if (t == 0) { mean1 = s1[0] / O_; mean2 = s2[0] / O_; }
    __syncthreads();
    float d1 = a - mean1, d2 = b - mean2;
    s1[t] = d1 * d1; s2[t] = d2 * d2; __syncthreads();
    for (int s = 512; s > 0; s >>= 1) {
        if (t < s) { s1[t] += s1[t + s]; s2[t] += s2[t + s]; }
        __syncthreads();
    }
    if (t == 0) {
        float var1 = s1[0] / (O_ - 1), var2 = s2[0] / (O_ - 1);
        const float eps = 1e-10f;
        out_loss[0] = (var1 / (mean1 * mean1 + eps) + var2 / (mean2 * mean2 + eps)) * LOSS_COEF;
    }
}

// ---------------------------------------------------------------------------
// per-expert fused MLP: h = relu(X_e @ w1[e] + b1[e]) * gate; y += h @ w2[e]
// 64x64 h-tile per block, fp32, 4x4 micro-tile per thread
// ---------------------------------------------------------------------------
__global__ __launch_bounds__(256) void expert_gemm_kernel(
    const float* __restrict__ obs, const float* __restrict__ w1,
    const float* __restrict__ b1, const float* __restrict__ w2,
    const int* __restrict__ cnt, const int* __restrict__ rows,
    const float* __restrict__ gatev, float* __restrict__ y)
{
    const int ht = blockIdx.x;       // h tile: 0..31
    const int rt = blockIdx.y;       // row tile: 0..15 (worst case)
    const int e  = blockIdx.z;
    const int n  = cnt[e];
    const int r0 = rt * BM;
    if (r0 >= n) return;             // uniform early-exit
    const int t = threadIdx.x;

    __shared__ float As[BK][BM];
    __shared__ float Bs[BK][BN];
    __shared__ int   rid[BM];
    __shared__ float rgate[BM];
    __shared__ float Hs[BM][BN + 1];
    __shared__ float W2s[BN][A_];

    if (t < BM) {
        int gi = r0 + t;
        if (gi < n) { rid[t] = rows[e * O_ + gi]; rgate[t] = gatev[e * O_ + gi]; }
        else        { rid[t] = -1;                rgate[t] = 0.f; }
    }
    __syncthreads();

    const int tx = t & 15, ty = t >> 4;
    const int ar = t >> 2, akq = t & 3;      // A staging: 64 rows x 4 k-quads
    const int bkr = t >> 4, bn4 = t & 15;    // B staging: 16 k-rows x 16 n-quads
    const int arow = rid[ar];
    const float* w1e = w1 + (size_t)e * (D_ * H_) + (size_t)ht * BN;

    float c[4][4] = {};

    for (int k0 = 0; k0 < D_; k0 += BK) {
        float4 av = make_float4(0.f, 0.f, 0.f, 0.f);
        if (arow >= 0)
            av = *(const float4*)(obs + (size_t)arow * D_ + k0 + akq * 4);
        As[akq * 4 + 0][ar] = av.x;
        As[akq * 4 + 1][ar] = av.y;
        As[akq * 4 + 2][ar] = av.z;
        As[akq * 4 + 3][ar] = av.w;
        float4 bv = *(const float4*)(w1e + (size_t)(k0 + bkr) * H_ + bn4 * 4);
        *(float4*)&Bs[bkr][bn4 * 4] = bv;
        __syncthreads();
        #pragma unroll
        for (int k = 0; k < BK; ++k) {
            float4 a4v = *(const float4*)&As[k][ty * 4];
            float4 b4v = *(const float4*)&Bs[k][tx * 4];
            c[0][0] += a4v.x * b4v.x; c[0][1] += a4v.x * b4v.y; c[0][2] += a4v.x * b4v.z; c[0][3] += a4v.x * b4v.w;
            c[1][0] += a4v.y * b4v.x; c[1][1] += a4v.y * b4v.y; c[1][2] += a4v.y * b4v.z; c[1][3] += a4v.y * b4v.w;
            c[2][0] += a4v.z * b4v.x; c[2][1] += a4v.z * b4v.y; c[2][2] += a4v.z * b4v.z; c[2][3] += a4v.z * b4v.w;
            c[3][0] += a4v.w * b4v.x; c[3][1] += a4v.w * b4v.y; c[3][2] += a4v.w * b4v.z; c[3][3] += a4v.w * b4v.w;
        }
        __syncthreads();
    }

    // epilogue 1: relu(c + b1)*gate -> Hs
    const float* b1e = b1 + (size_t)e * H_ + (size_t)ht * BN;
    float bb[4];
    #pragma unroll
    for (int j = 0; j < 4; ++j) bb[j] = b1e[tx * 4 + j];
    #pragma unroll
    for (int i = 0; i < 4; ++i) {
        float g = rgate[ty * 4 + i];
        #pragma unroll
        for (int j = 0; j < 4; ++j) {
            float h = c[i][j] + bb[j];
            h = h > 0.f ? h : 0.f;
            Hs[ty * 4 + i][tx * 4 + j] = h * g;
        }
    }
    // stage w2 tile [64 hcols x 64 a]
    const float* w2e = w2 + (size_t)e * (H_ * A_) + (size_t)ht * BN * A_;
    #pragma unroll
    for (int i = 0; i < 4; ++i) {
        int idx4 = t + i * 256;
        int hh = idx4 >> 4, a4 = idx4 & 15;
        *(float4*)&W2s[hh][a4 * 4] = *(const float4*)(w2e + (size_t)hh * A_ + a4 * 4);
    }
    __syncthreads();

    // epilogue 2: y_part[64 rows][64 a] = Hs @ W2s
    float c2[4][4] = {};
    #pragma unroll 8
    for (int kk = 0; kk < BN; ++kk) {
        float4 wv = *(const float4*)&W2s[kk][tx * 4];
        float h0 = Hs[ty * 4 + 0][kk];
        float h1 = Hs[ty * 4 + 1][kk];
        float h2 = Hs[ty * 4 + 2][kk];
        float h3 = Hs[ty * 4 + 3][kk];
        c2[0][0] += h0 * wv.x; c2[0][1] += h0 * wv.y; c2[0][2] += h0 * wv.z; c2[0][3] += h0 * wv.w;
        c2[1][0] += h1 * wv.x; c2[1][1] += h1 * wv.y; c2[1][2] += h1 * wv.z; c2[1][3] += h1 * wv.w;
        c2[2][0] += h2 * wv.x; c2[2][1] += h2 * wv.y; c2[2][2] += h2 * wv.z; c2[2][3] += h2 * wv.w;
        c2[3][0] += h3 * wv.x; c2[3][1] += h3 * wv.y; c2[3][2] += h3 * wv.z; c2[3][3] += h3 * wv.w;
    }
    #pragma unroll
    for (int i = 0; i < 4; ++i) {
        int r = rid[ty * 4 + i];
        if (r >= 0) {
            #pragma unroll
            for (int j = 0; j < 4; ++j)
                atomicAdd(&y[(size_t)r * A_ + tx * 4 + j], c2[i][j]);
        }
    }
}

// ---------------------------------------------------------------------------
// action head: mu = obs[o,:] @ last_w[o] + last_b[o]; softmax + z-trick log
// fp32 throughout; software-FTZ on exp and p to match the np reference's
// flush-to-zero environment (decides the p==0 -> log(1e-8) branch).
// ---------------------------------------------------------------------------
__global__ __launch_bounds__(256) void action_head_kernel(
    const float* __restrict__ obs, const float* __restrict__ last_w,
    const float* __restrict__ last_b,
    float* __restrict__ probs, float* __restrict__ logprobs)
{
    const int o = blockIdx.x;
    const int t = threadIdx.x;
    __shared__ float xs[D_];
    __shared__ float red[16][A_];

    const float4* xrow = (const float4*)(obs + (size_t)o * D_);
    for (int i = t; i < D_ / 4; i += 256) ((float4*)xs)[i] = xrow[i];
    __syncthreads();

    const int a4 = t & 15, dg = t >> 4;
    const float* lw = last_w + (size_t)o * (D_ * A_);
    float acc0 = 0.f, acc1 = 0.f, acc2 = 0.f, acc3 = 0.f;
    #pragma unroll 4
    for (int i = 0; i < D_ / 16; ++i) {
        int d = dg + (i << 4);
        float4 w = *(const float4*)(lw + (size_t)d * A_ + a4 * 4);  // fully coalesced
        float x = xs[d];
        acc0 += x * w.x; acc1 += x * w.y; acc2 += x * w.z; acc3 += x * w.w;
    }
    *(float4*)&red[dg][a4 * 4] = make_float4(acc0, acc1, acc2, acc3);
    __syncthreads();

    if (t < A_) {   // one wave does the softmax
        float mu = last_b[(size_t)o * A_ + t];
        #pragma unroll
        for (int g = 0; g < 16; ++g) mu += red[g][t];
        float mx = mu;
        #pragma unroll
        for (int off = 32; off > 0; off >>= 1) mx = fmaxf(mx, __shfl_xor(mx, off, 64));
        float ex = expf(mu - mx);
        if (ex < FLT_MIN_NORMAL) ex = 0.f;            // software FTZ (match np ref)
        float s = ex;
        #pragma unroll
        for (int off = 32; off > 0; off >>= 1) s += __shfl_xor(s, off, 64);
        float p = ex / s;
        if (p < FLT_MIN_NORMAL) p = 0.f;              // software FTZ (match np ref)
        probs[(size_t)o * A_ + t] = p;
        float z = (p == 0.f) ? 1e-8f : 0.f;
        logprobs[(size_t)o * A_ + t] = logf(p + z);
    }
}

// ---------------------------------------------------------------------------
extern "C" void kernel_launch(void* const* d_in, const int* in_sizes, int n_in,
                              void* d_out, int out_size, void* d_ws, size_t ws_size,
                              hipStream_t stream)
{
    const float* obs    = (const float*)d_in[0];
    const float* w_gate = (const float*)d_in[1];
    const float* w1     = (const float*)d_in[2];
    const float* b1     = (const float*)d_in[3];
    const float* w2     = (const float*)d_in[4];
    const float* b2     = (const float*)d_in[5];
    const float* last_w = (const float*)d_in[6];
    const float* last_b = (const float*)d_in[7];

    float* out   = (float*)d_out;
    float* probs = out;                 // [O,A]
    float* logp  = out + O_ * A_;       // [O,A]
    float* yout  = out + 2 * O_ * A_;   // [O,A]
    float* loss  = out + 3 * O_ * A_;   // [1]

    char* ws = (char*)d_ws;
    int*   topk_idx  = (int*)(ws);                    // 4096 ints
    float* topk_gate = (float*)(ws + 16384);          // 4096 f
    float* imp       = (float*)(ws + 32768);          // 1024 f
    float* loadv     = (float*)(ws + 36864);          // 1024 f
    int*   cnt       = (int*)(ws + 40960);            // 16 ints
    int*   rows      = (int*)(ws + 41984);            // 16384 ints
    float* gatev     = (float*)(ws + 41984 + 65536);  // 16384 f

    hipLaunchKernelGGL(zero_cnt_kernel, dim3(1), dim3(64), 0, stream, cnt);
    hipLaunchKernelGGL(gating_kernel, dim3(O_), dim3(256), 0, stream,
                       obs, w_gate, topk_idx, topk_gate, imp, loadv);
    hipLaunchKernelGGL(build_dispatch_kernel, dim3((O_ * K_) / 256), dim3(256), 0, stream,
                       topk_idx, topk_gate, cnt, rows, gatev);
    hipLaunchKernelGGL(y_init_kernel, dim3(O_), dim3(A_), 0, stream,
                       topk_idx, topk_gate, b2, yout);
    hipLaunchKernelGGL(loss_kernel, dim3(1), dim3(1024), 0, stream, imp, loadv, loss);
    hipLaunchKernelGGL(expert_gemm_kernel, dim3(H_ / BN, O_ / BM, E_), dim3(256), 0, stream,
                       obs, w1, b1, w2, cnt, rows, gatev, yout);
    hipLaunchKernelGGL(action_head_kernel, dim3(O_), dim3(256), 0, stream,
                       obs, last_w, last_b, probs, logp);
}

// Round 3
// 690.060 us; speedup vs baseline: 1.1818x; 1.1818x over previous
//
#include <hip/hip_runtime.h>
#include <hip/hip_bf16.h>
#include <math.h>

#define O_ 1024
#define D_ 1024
#define E_ 16
#define K_ 4
#define H_ 2048
#define A_ 64
#define LOSS_COEF 0.01f

// np reference runs FTZ/DAZ (its min logprob is log(FLT_MIN)); gfx950 keeps
// IEEE denormals. Software-flush at the two decision points. (R1-verified.)
#define FLT_MIN_NORMAL 1.17549435e-38f

using floatx4 = __attribute__((ext_vector_type(4))) float;
using fragb   = __attribute__((ext_vector_type(8))) short;   // 8 bf16 in 4 VGPRs

static __device__ __forceinline__ ushort f2bf(float f) {
    // round-to-nearest-even fp32 -> bf16
    unsigned u = __builtin_bit_cast(unsigned, f);
    u += 0x7fffu + ((u >> 16) & 1u);
    return (ushort)(u >> 16);
}

// ---------------------------------------------------------------------------
// gating (fp32: top-k selection + FTZ path are bf16-intolerant)
// ---------------------------------------------------------------------------
__global__ __launch_bounds__(256) void gating_kernel(
    const float* __restrict__ obs, const float* __restrict__ w_gate,
    int* __restrict__ topk_idx, float* __restrict__ topk_gate,
    float* __restrict__ imp, float* __restrict__ loadv)
{
    const int o = blockIdx.x;
    const int t = threadIdx.x;
    __shared__ float xs[D_];
    __shared__ float part[64][20];     // [d-group][e] padded (f4 bank spread)
    __shared__ float logits[E_];

    const float4* xrow = (const float4*)(obs + (size_t)o * D_);
    for (int i = t; i < D_ / 4; i += 256) ((float4*)xs)[i] = xrow[i];
    __syncthreads();

    const int dg = t >> 2, e4 = t & 3;
    const float4* wg = (const float4*)(w_gate + (size_t)o * (D_ * E_));
    float4 acc = make_float4(0.f, 0.f, 0.f, 0.f);
    #pragma unroll 4
    for (int i = 0; i < 16; ++i) {
        int d = dg + (i << 6);
        float4 w = wg[d * 4 + e4];     // f4 idx = t + 256*i : coalesced 16B/lane
        float x = xs[d];
        acc.x += x * w.x; acc.y += x * w.y; acc.z += x * w.z; acc.w += x * w.w;
    }
    *(float4*)&part[dg][e4 * 4] = acc;
    __syncthreads();
    if (t < E_) {
        float s = 0.f;
        for (int g = 0; g < 64; ++g) s += part[g][t];
        logits[t] = s;
    }
    __syncthreads();
    if (t == 0) {
        float lv[E_];
        #pragma unroll
        for (int i = 0; i < E_; ++i) lv[i] = logits[i];
        int idx[K_]; float val[K_];
        bool used[E_] = {};
        for (int k = 0; k < K_; ++k) {            // desc, ties -> lower idx
            int bi = 0; float bv = -INFINITY;
            for (int i = 0; i < E_; ++i)
                if (!used[i] && lv[i] > bv) { bv = lv[i]; bi = i; }
            used[bi] = true; idx[k] = bi; val[k] = bv;
        }
        float m = val[0];
        float ex[K_]; float s = 0.f;
        for (int k = 0; k < K_; ++k) { ex[k] = expf(val[k] - m); s += ex[k]; }
        float inv = 1.f / s;
        float sumg = 0.f; int ld = 0;
        for (int k = 0; k < K_; ++k) {
            float g = ex[k] * inv;
            topk_idx[o * K_ + k] = idx[k];
            topk_gate[o * K_ + k] = g;
            sumg += g;
            if (g > 0.f) ld++;
        }
        imp[o] = sumg;
        loadv[o] = (float)ld;
    }
}

// ---------------------------------------------------------------------------
__global__ void zero_cnt_kernel(int* __restrict__ cnt)
{
    if (threadIdx.x < E_) cnt[threadIdx.x] = 0;
}

__global__ __launch_bounds__(256) void build_dispatch_kernel(
    const int* __restrict__ topk_idx, const float* __restrict__ topk_gate,
    int* __restrict__ cnt, int* __restrict__ rows, float* __restrict__ gatev)
{
    int i = blockIdx.x * 256 + threadIdx.x;      // 0..O*K-1
    int e = topk_idx[i];
    int pos = atomicAdd(&cnt[e], 1);
    rows[e * O_ + pos] = i >> 2;
    gatev[e * O_ + pos] = topk_gate[i];
}

// y[o,a] = sum_k gate[o,k]*b2[e_k,a]  (init; MFMA kernel atomicAdds on top)
__global__ __launch_bounds__(64) void y_init_kernel(
    const int* __restrict__ topk_idx, const float* __restrict__ topk_gate,
    const float* __restrict__ b2, float* __restrict__ y)
{
    int o = blockIdx.x, a = threadIdx.x;
    float acc = 0.f;
    #pragma unroll
    for (int k = 0; k < K_; ++k) {
        int e = topk_idx[o * K_ + k];
        acc += topk_gate[o * K_ + k] * b2[e * A_ + a];
    }
    y[(size_t)o * A_ + a] = acc;
}

// ---------------------------------------------------------------------------
__global__ __launch_bounds__(1024) void loss_kernel(
    const float* __restrict__ imp, const float* __restrict__ loadv,
    float* __restrict__ out_loss)
{
    __shared__ float s1[1024], s2[1024];
    __shared__ float mean1, mean2;
    int t = threadIdx.x;
    float a = imp[t], b = loadv[t];
    s1[t] = a; s2[t] = b; __syncthreads();
    for (int s = 512; s > 0; s >>= 1) {
        if (t < s) { s1[t] += s1[t + s]; s2[t] += s2[t + s]; }
        __syncthreads();
    }
    if (t == 0) { mean1 = s1[0] / O_; mean2 = s2[0] / O_; }
    __syncthreads();
    float d1 = a - mean1, d2 = b - mean2;
    s1[t] = d1 * d1; s2[t] = d2 * d2; __syncthreads();
    for (int s = 512; s > 0; s >>= 1) {
        if (t < s) { s1[t] += s1[t + s]; s2[t] += s2[t + s]; }
        __syncthreads();
    }
    if (t == 0) {
        float var1 = s1[0] / (O_ - 1), var2 = s2[0] / (O_ - 1);
        const float eps = 1e-10f;
        out_loss[0] = (var1 / (mean1 * mean1 + eps) + var2 / (mean2 * mean2 + eps)) * LOSS_COEF;
    }
}

// ---------------------------------------------------------------------------
// conversions: obs -> bf16; src[E][R][C] f32 -> dst[E][C][R] bf16 (transpose)
// ---------------------------------------------------------------------------
__global__ __launch_bounds__(256) void cvt_obs_kernel(
    const float* __restrict__ src, ushort* __restrict__ dst)
{
    int i = blockIdx.x * 256 + threadIdx.x;       // float4 index
    float4 v = ((const float4*)src)[i];
    ushort4 u;
    u.x = f2bf(v.x); u.y = f2bf(v.y); u.z = f2bf(v.z); u.w = f2bf(v.w);
    ((ushort4*)dst)[i] = u;
}

__global__ __launch_bounds__(256) void transpose_bf16_kernel(
    const float* __restrict__ src, ushort* __restrict__ dst, int R, int C)
{
    const int c0 = blockIdx.x * 64, r0 = blockIdx.y * 64, e = blockIdx.z;
    __shared__ ushort tile[64][72];               // +8 pad
    const float* s = src + (size_t)e * R * C;
    const int t = threadIdx.x;
    const int rr = t >> 4, cq = t & 15;
    #pragma unroll
    for (int i = 0; i < 4; ++i) {
        int r = rr + i * 16;
        float4 v = *(const float4*)(s + (size_t)(r0 + r) * C + c0 + cq * 4);
        ushort4 u;
        u.x = f2bf(v.x); u.y = f2bf(v.y); u.z = f2bf(v.z); u.w = f2bf(v.w);
        *(ushort4*)&tile[r][cq * 4] = u;
    }
    __syncthreads();
    ushort* dbase = dst + (size_t)e * R * C;
    const int cc = t >> 4, rq = t & 15;
    #pragma unroll
    for (int i = 0; i < 4; ++i) {
        int c = cc + i * 16;
        ushort4 u;
        u.x = tile[rq * 4 + 0][c];
        u.y = tile[rq * 4 + 1][c];
        u.z = tile[rq * 4 + 2][c];
        u.w = tile[rq * 4 + 3][c];
        *(ushort4*)(dbase + (size_t)(c0 + c) * R + r0 + rq * 4) = u;
    }
}

// ---------------------------------------------------------------------------
// fused expert MLP, bf16 MFMA 16x16x32:
//   layer1: h = relu(X_e @ w1[e] + b1[e]) * gate   (A=obs_bf rows, B=w1T[h][d])
//   layer2: y += h @ w2[e]                          (A=Hs LDS,     B=w2T[a][h])
// block = (h-tile 64, row-tile 64, expert); 4 waves x 16-row strips
// ---------------------------------------------------------------------------
__global__ __launch_bounds__(256) void expert_mfma_kernel(
    const ushort* __restrict__ obs_bf, const ushort* __restrict__ w1T,
    const float* __restrict__ b1, const ushort* __restrict__ w2T,
    const int* __restrict__ cnt, const int* __restrict__ rows,
    const float* __restrict__ gatev, float* __restrict__ y)
{
    const int ht = blockIdx.x, rt = blockIdx.y, e = blockIdx.z;
    const int n = cnt[e];
    if (rt * 64 >= n) return;                     // uniform early-exit
    const int t = threadIdx.x, wv = t >> 6, l = t & 63;
    const int lm = l & 15, q = l >> 4;

    __shared__ int   rid[64];
    __shared__ float rgate[64];
    __shared__ float b1s[64];
    __shared__ ushort Hs[64][72];                 // stride 72 (144B = 16B*9)

    if (t < 64) {
        int gi = rt * 64 + t;
        rid[t]   = (gi < n) ? rows[e * O_ + gi]  : -1;
        rgate[t] = (gi < n) ? gatev[e * O_ + gi] : 0.f;
        b1s[t]   = b1[e * H_ + ht * 64 + t];
    }
    __syncthreads();

    // ---- layer 1: acc[nt] = X(16 rows) @ w1T(4 n-tiles of 16 h) over K=1024
    int arow = rid[wv * 16 + lm]; if (arow < 0) arow = 0;  // gate=0 kills junk
    const ushort* ap = obs_bf + (size_t)arow * D_ + q * 8;
    const ushort* bp = w1T + ((size_t)(e * H_ + ht * 64 + lm)) * D_ + q * 8;

    floatx4 acc[4] = {};
    #pragma unroll 2
    for (int k0 = 0; k0 < D_; k0 += 32) {
        fragb a  = *(const fragb*)(ap + k0);
        fragb b0 = *(const fragb*)(bp + k0);
        fragb b1f = *(const fragb*)(bp + 16 * D_ + k0);
        fragb b2f = *(const fragb*)(bp + 32 * D_ + k0);
        fragb b3f = *(const fragb*)(bp + 48 * D_ + k0);
        acc[0] = __builtin_amdgcn_mfma_f32_16x16x32_bf16(a, b0,  acc[0], 0, 0, 0);
        acc[1] = __builtin_amdgcn_mfma_f32_16x16x32_bf16(a, b1f, acc[1], 0, 0, 0);
        acc[2] = __builtin_amdgcn_mfma_f32_16x16x32_bf16(a, b2f, acc[2], 0, 0, 0);
        acc[3] = __builtin_amdgcn_mfma_f32_16x16x32_bf16(a, b3f, acc[3], 0, 0, 0);
    }

    // ---- epilogue 1: relu(acc+b1)*gate -> Hs (C layout: row=q*4+r, col=nt*16+lm)
    const int r0 = wv * 16 + q * 4;
    #pragma unroll
    for (int nt = 0; nt < 4; ++nt) {
        int col = nt * 16 + lm;
        float bb = b1s[col];
        #pragma unroll
        for (int r = 0; r < 4; ++r) {
            float h = acc[nt][r] + bb;
            h = h > 0.f ? h : 0.f;
            Hs[r0 + r][col] = f2bf(h * rgate[r0 + r]);
        }
    }
    __syncthreads();

    // ---- layer 2: acc2 = Hs(16 rows x 64 h) @ w2T(4 n-tiles of 16 a)
    const ushort* hp = &Hs[wv * 16 + lm][q * 8];
    const ushort* wp = w2T + ((size_t)(e * A_ + lm)) * H_ + ht * 64 + q * 8;
    floatx4 acc2[4] = {};
    #pragma unroll
    for (int k = 0; k < 2; ++k) {
        fragb a = *(const fragb*)(hp + k * 32);
        #pragma unroll
        for (int nt = 0; nt < 4; ++nt) {
            fragb b = *(const fragb*)(wp + (size_t)nt * 16 * H_ + k * 32);
            acc2[nt] = __builtin_amdgcn_mfma_f32_16x16x32_bf16(a, b, acc2[nt], 0, 0, 0);
        }
    }

    // ---- epilogue 2: scatter-add into y
    #pragma unroll
    for (int r = 0; r < 4; ++r) {
        int orow = rid[r0 + r];
        if (orow >= 0) {
            #pragma unroll
            for (int nt = 0; nt < 4; ++nt)
                atomicAdd(&y[(size_t)orow * A_ + nt * 16 + lm], acc2[nt][r]);
        }
    }
}

// ---------------------------------------------------------------------------
// action head (fp32; software-FTZ decides the p==0 -> log(1e-8) branch)
// ---------------------------------------------------------------------------
__global__ __launch_bounds__(256) void action_head_kernel(
    const float* __restrict__ obs, const float* __restrict__ last_w,
    const float* __restrict__ last_b,
    float* __restrict__ probs, float* __restrict__ logprobs)
{
    const int o = blockIdx.x;
    const int t = threadIdx.x;
    __shared__ float xs[D_];
    __shared__ float red[16][A_];

    const float4* xrow = (const float4*)(obs + (size_t)o * D_);
    for (int i = t; i < D_ / 4; i += 256) ((float4*)xs)[i] = xrow[i];
    __syncthreads();

    const int a4 = t & 15, dg = t >> 4;
    const float* lw = last_w + (size_t)o * (D_ * A_);
    float acc0 = 0.f, acc1 = 0.f, acc2 = 0.f, acc3 = 0.f;
    #pragma unroll 8
    for (int i = 0; i < D_ / 16; ++i) {
        int d = dg + (i << 4);
        float4 w = *(const float4*)(lw + (size_t)d * A_ + a4 * 4);  // coalesced
        float x = xs[d];
        acc0 += x * w.x; acc1 += x * w.y; acc2 += x * w.z; acc3 += x * w.w;
    }
    *(float4*)&red[dg][a4 * 4] = make_float4(acc0, acc1, acc2, acc3);
    __syncthreads();

    if (t < A_) {   // one wave does the softmax
        float mu = last_b[(size_t)o * A_ + t];
        #pragma unroll
        for (int g = 0; g < 16; ++g) mu += red[g][t];
        float mx = mu;
        #pragma unroll
        for (int off = 32; off > 0; off >>= 1) mx = fmaxf(mx, __shfl_xor(mx, off, 64));
        float ex = expf(mu - mx);
        if (ex < FLT_MIN_NORMAL) ex = 0.f;            // software FTZ
        float s = ex;
        #pragma unroll
        for (int off = 32; off > 0; off >>= 1) s += __shfl_xor(s, off, 64);
        float p = ex / s;
        if (p < FLT_MIN_NORMAL) p = 0.f;              // software FTZ
        probs[(size_t)o * A_ + t] = p;
        float z = (p == 0.f) ? 1e-8f : 0.f;
        logprobs[(size_t)o * A_ + t] = logf(p + z);
    }
}

// ---------------------------------------------------------------------------
extern "C" void kernel_launch(void* const* d_in, const int* in_sizes, int n_in,
                              void* d_out, int out_size, void* d_ws, size_t ws_size,
                              hipStream_t stream)
{
    const float* obs    = (const float*)d_in[0];
    const float* w_gate = (const float*)d_in[1];
    const float* w1     = (const float*)d_in[2];
    const float* b1     = (const float*)d_in[3];
    const float* w2     = (const float*)d_in[4];
    const float* b2     = (const float*)d_in[5];
    const float* last_w = (const float*)d_in[6];
    const float* last_b = (const float*)d_in[7];

    float* out   = (float*)d_out;
    float* probs = out;                 // [O,A]
    float* logp  = out + O_ * A_;       // [O,A]
    float* yout  = out + 2 * O_ * A_;   // [O,A]
    float* loss  = out + 3 * O_ * A_;   // [1]

    char* ws = (char*)d_ws;
    int*    topk_idx  = (int*)(ws);                         // 16 KB
    float*  topk_gate = (float*)(ws + (16 << 10));          // 16 KB
    float*  imp       = (float*)(ws + (32 << 10));          // 4 KB
    float*  loadv     = (float*)(ws + (36 << 10));          // 4 KB
    int*    cnt       = (int*)(ws + (40 << 10));            // 64 B
    int*    rows      = (int*)(ws + (41 << 10));            // 64 KB
    float*  gatev     = (float*)(ws + (105 << 10));         // 64 KB
    ushort* obs_bf    = (ushort*)(ws + (256 << 10));        // 2 MB
    ushort* w1T       = (ushort*)(ws + (256 << 10) + (2 << 20));   // 64 MB
    ushort* w2T       = (ushort*)(ws + (256 << 10) + (66 << 20));  // 4 MB

    hipLaunchKernelGGL(zero_cnt_kernel, dim3(1), dim3(64), 0, stream, cnt);
    hipLaunchKernelGGL(gating_kernel, dim3(O_), dim3(256), 0, stream,
                       obs, w_gate, topk_idx, topk_gate, imp, loadv);
    hipLaunchKernelGGL(build_dispatch_kernel, dim3((O_ * K_) / 256), dim3(256), 0, stream,
                       topk_idx, topk_gate, cnt, rows, gatev);
    hipLaunchKernelGGL(y_init_kernel, dim3(O_), dim3(A_), 0, stream,
                       topk_idx, topk_gate, b2, yout);
    hipLaunchKernelGGL(loss_kernel, dim3(1), dim3(1024), 0, stream, imp, loadv, loss);

    hipLaunchKernelGGL(cvt_obs_kernel, dim3((O_ * D_) / 1024), dim3(256), 0, stream,
                       obs, obs_bf);
    hipLaunchKernelGGL(transpose_bf16_kernel, dim3(H_ / 64, D_ / 64, E_), dim3(256), 0, stream,
                       w1, w1T, D_, H_);
    hipLaunchKernelGGL(transpose_bf16_kernel, dim3(A_ / 64, H_ / 64, E_), dim3(256), 0, stream,
                       w2, w2T, H_, A_);

    hipLaunchKernelGGL(expert_mfma_kernel, dim3(H_ / 64, O_ / 64, E_), dim3(256), 0, stream,
                       obs_bf, w1T, b1, w2T, cnt, rows, gatev, yout);
    hipLaunchKernelGGL(action_head_kernel, dim3(O_), dim3(256), 0, stream,
                       obs, last_w, last_b, probs, logp);
}